// Round 18
// baseline (47.585 us; speedup 1.0000x reference)
//
#include <hip/hip_runtime.h>
#include <math.h>

#define LQ 256
#define MEML 256
#define LK 512
#define BB 4
#define NH 8
#define DM 128

#define IT 4                  // i-tile per score block (24 KB LDS)

constexpr float INV2PI = 0.15915494309189535f;

// ---------------------------------------------------------------------------
// Projection + sincos tables, pre-scaled by paramR[h]/(2*pi):
//   qT[(i*32+b*8+h)*48 + {d, 16+d, 32+d}] = {v, sin2pi(v), cos2pi(v)}
//   kT{v,s,c}[((d>>2)*512 + j)*128 + (b*8+h)*4 + (d&3)]  (plane-major)
// ---------------------------------------------------------------------------
__global__ __launch_bounds__(128) void proj_kernel(
    const float* __restrict__ hh, const float* __restrict__ mems,
    const float* __restrict__ Wq, const float* __restrict__ Wk,
    const float* __restrict__ paramR,
    float* __restrict__ qT,
    float* __restrict__ kTv, float* __restrict__ kTs, float* __restrict__ kTc)
{
    __shared__ float x[8 * 128];
    const int blk = blockIdx.x;
    const int t = threadIdx.x;
    const bool isQ = (blk < 128);                 // 128 q-blocks, 256 k-blocks
    const int row0 = isQ ? blk * 8 : (blk - 128) * 8;
    const float* __restrict__ W = isQ ? Wq : Wk;

    for (int r = 0; r < 8; ++r) {
        const int row = row0 + r;
        const float* src = isQ ? (hh + row * DM)
                               : ((row < MEML * BB) ? (mems + row * DM)
                                                    : (hh + (row - MEML * BB) * DM));
        x[r * 128 + t] = src[t];
    }
    __syncthreads();

    float acc[8] = {0, 0, 0, 0, 0, 0, 0, 0};
    const float* wrow = W + t * DM;
    for (int k = 0; k < DM; k += 4) {
        const float4 w = *(const float4*)(wrow + k);
        #pragma unroll
        for (int r = 0; r < 8; ++r) {
            acc[r] += x[r * 128 + k + 0] * w.x + x[r * 128 + k + 1] * w.y
                    + x[r * 128 + k + 2] * w.z + x[r * 128 + k + 3] * w.w;
        }
    }
    const int h = t >> 4, d = t & 15;
    const float rs = paramR[h] * INV2PI;
    #pragma unroll
    for (int r = 0; r < 8; ++r) {
        const int row = row0 + r;
        const int b = row & 3;
        const float v = acc[r] * rs;
        const float sn = __builtin_amdgcn_sinf(v);    // sin(2pi*v)
        const float cs = __builtin_amdgcn_cosf(v);    // cos(2pi*v)
        if (isQ) {
            const int i = row >> 2;
            float* qp = qT + (i * 32 + b * 8 + h) * 48;
            qp[d] = v; qp[16 + d] = sn; qp[32 + d] = cs;
        } else {
            const int j = row >> 2;
            const int idx = ((d >> 2) * LK + j) * 128 + (b * 8 + h) * 4 + (d & 3);
            kTv[idx] = v; kTs[idx] = sn; kTc[idx] = cs;
        }
    }
}

// ---------------------------------------------------------------------------
// Score, ZERO transcendentals in the hot loop (R12 shell):
//   num = qs*kc - qc*ks  (= sin(2pi(q-k)));  factor = num/(2pi*dl)
//   guard |dl|<=EPS -> (num,dl) := (1, 1/2pi)  => factor == 1
// k-tables (48 VGPR) loaded once/thread; q-tables staged in LDS per block
// (IT=4, 24 KB); per d: 8 cheap VALU ops (16 cyc) vs 24 cyc with v_sin.
// ---------------------------------------------------------------------------
__global__ __launch_bounds__(256, 4) void score_kernel(
    const float* __restrict__ qT,
    const float* __restrict__ kTv, const float* __restrict__ kTs,
    const float* __restrict__ kTc,
    float* __restrict__ out)
{
    __shared__ float qt[IT * 32 * 48];            // 24576 B
    const int t = threadIdx.x;
    const int bh = t & 31;
    const int js = t >> 5;                        // 0..7
    const int i0 = blockIdx.x * IT;               // 64 i-tiles
    const int j = blockIdx.y * 8 + js;            // 64 j-tiles of 8

    constexpr float i2 = INV2PI * INV2PI;
    constexpr float i4 = i2 * i2;
    constexpr float i8 = i4 * i4;
    constexpr float C16 = i8 * i8;                // (2pi)^-16
    constexpr float EPS = 2.0e-4f * INV2PI;       // 3.18e-5 rev

    // stage q-tables: IT*32*48 = 6144 floats = 1536 float4 chunks
    {
        const float* src = qT + i0 * 32 * 48;
        #pragma unroll
        for (int rep = 0; rep < 6; ++rep) {
            const int c4 = rep * 256 + t;
            *(float4*)(&qt[c4 * 4]) = *(const float4*)(src + c4 * 4);
        }
    }

    // k sincos tables resident in 48 VGPRs (coalesced plane-major loads)
    float kv[16], ks[16], kc[16];
    #pragma unroll
    for (int s = 0; s < 4; ++s) {
        const int off = (s * LK + j) * 128 + bh * 4;
        const float4 a = *(const float4*)(kTv + off);
        const float4 b = *(const float4*)(kTs + off);
        const float4 c = *(const float4*)(kTc + off);
        kv[s*4+0] = a.x; kv[s*4+1] = a.y; kv[s*4+2] = a.z; kv[s*4+3] = a.w;
        ks[s*4+0] = b.x; ks[s*4+1] = b.y; ks[s*4+2] = b.z; ks[s*4+3] = b.w;
        kc[s*4+0] = c.x; kc[s*4+1] = c.y; kc[s*4+2] = c.z; kc[s*4+3] = c.w;
    }
    __syncthreads();

    #pragma unroll
    for (int ii = 0; ii < IT; ++ii) {
        const float* qrow = &qt[(ii * 32 + bh) * 48];
        float qv[16], qs_[16], qc_[16];
        #pragma unroll
        for (int s = 0; s < 4; ++s) {
            const float4 a = *(const float4*)(qrow + s * 4);
            const float4 b = *(const float4*)(qrow + 16 + s * 4);
            const float4 c = *(const float4*)(qrow + 32 + s * 4);
            qv[s*4+0] = a.x; qv[s*4+1] = a.y; qv[s*4+2] = a.z; qv[s*4+3] = a.w;
            qs_[s*4+0] = b.x; qs_[s*4+1] = b.y; qs_[s*4+2] = b.z; qs_[s*4+3] = b.w;
            qc_[s*4+0] = c.x; qc_[s*4+1] = c.y; qc_[s*4+2] = c.z; qc_[s*4+3] = c.w;
        }
        float pn0 = 1.f, pd0 = 1.f, pn1 = 1.f, pd1 = 1.f;
        #pragma unroll
        for (int d = 0; d < 16; ++d) {
            const float dl  = qv[d] - kv[d];
            const float m1  = qc_[d] * ks[d];
            const float num = __builtin_fmaf(qs_[d], kc[d], -m1);  // sin(2pi*dl)
            const bool  g   = __builtin_fabsf(dl) > EPS;
            const float nn  = g ? num : 1.0f;
            const float dd  = g ? dl : INV2PI;
            if (d < 8) { pn0 *= nn; pd0 *= dd; }
            else       { pn1 *= nn; pd1 *= dd; }
        }
        const float r0 = pn0 * __builtin_amdgcn_rcpf(pd0);
        const float r1 = pn1 * __builtin_amdgcn_rcpf(pd1);
        out[((i0 + ii) * LK + j) * 32 + bh] = __builtin_fabsf(r0 * r1) * C16;
    }
}

extern "C" void kernel_launch(void* const* d_in, const int* in_sizes, int n_in,
                              void* d_out, int out_size, void* d_ws, size_t ws_size,
                              hipStream_t stream) {
    const float* hh     = (const float*)d_in[0];
    const float* mems   = (const float*)d_in[1];
    const float* Wq     = (const float*)d_in[2];
    const float* Wk     = (const float*)d_in[3];
    const float* paramR = (const float*)d_in[4];
    float* out = (float*)d_out;

    float* qT  = (float*)d_ws;                 // 8192*48 = 393216 floats
    float* kTv = qT  + LQ * BB * NH * 48;      // 262144 floats each
    float* kTs = kTv + LK * BB * DM;
    float* kTc = kTs + LK * BB * DM;

    proj_kernel<<<384, 128, 0, stream>>>(hh, mems, Wq, Wk, paramR,
                                         qT, kTv, kTs, kTc);
    score_kernel<<<dim3(LQ / IT, LK / 8), 256, 0, stream>>>(qT, kTv, kTs, kTc, out);
}

// Round 19
// 37.140 us; speedup vs baseline: 1.2812x; 1.2812x over previous
//
#include <hip/hip_runtime.h>
#include <math.h>

#define LQ 256
#define MEML 256
#define LK 512
#define BB 4
#define NH 8
#define DM 128

#define IT 8                  // i-tile per score block (20 KB LDS)
#define QSTRIDE 20            // LDS q row stride (floats)

constexpr float INV2PI = 0.15915494309189535f;

typedef float v2f __attribute__((ext_vector_type(2)));

// sin(2*pi*f) odd Taylor-13 coefficients (f in revolutions, |f|<=0.5)
#define SC1   6.2831853071795865f
#define SC3  -41.341702240399755f
#define SC5   81.60524927607504f
#define SC7  -76.70585975306136f
#define SC9   42.05869394489765f
#define SC11 -15.094642576059076f
#define SC13  3.8199525848482824f

// ---------------------------------------------------------------------------
// Projection (R12 structure), pre-scaled by paramR[h]/(2*pi), with PAIRED
// element order e = ((d&7)<<1)|(d>>3) so score loads (d, d+8) adjacently:
//   qs[(i*4+b)*128 + h*16 + e]
//   ksT[((e>>2)*512 + j)*128 + (b*8+h)*4 + (e&3)]
// ---------------------------------------------------------------------------
__global__ __launch_bounds__(128) void proj_kernel(
    const float* __restrict__ hh, const float* __restrict__ mems,
    const float* __restrict__ Wq, const float* __restrict__ Wk,
    const float* __restrict__ paramR,
    float* __restrict__ qs, float* __restrict__ ksT)
{
    __shared__ float x[8 * 128];
    const int blk = blockIdx.x;
    const int t = threadIdx.x;
    const bool isQ = (blk < 128);                 // 128 q-blocks, 256 k-blocks
    const int row0 = isQ ? blk * 8 : (blk - 128) * 8;
    const float* __restrict__ W = isQ ? Wq : Wk;

    for (int r = 0; r < 8; ++r) {
        const int row = row0 + r;
        const float* src = isQ ? (hh + row * DM)
                               : ((row < MEML * BB) ? (mems + row * DM)
                                                    : (hh + (row - MEML * BB) * DM));
        x[r * 128 + t] = src[t];
    }
    __syncthreads();

    float acc[8] = {0, 0, 0, 0, 0, 0, 0, 0};
    const float* wrow = W + t * DM;
    for (int k = 0; k < DM; k += 4) {
        const float4 w = *(const float4*)(wrow + k);
        #pragma unroll
        for (int r = 0; r < 8; ++r) {
            acc[r] += x[r * 128 + k + 0] * w.x + x[r * 128 + k + 1] * w.y
                    + x[r * 128 + k + 2] * w.z + x[r * 128 + k + 3] * w.w;
        }
    }
    const int h = t >> 4, d = t & 15;
    const int e = ((d & 7) << 1) | (d >> 3);      // pair-interleaved slot
    const float rs = paramR[h] * INV2PI;
    if (isQ) {
        float* dst = qs + row0 * 128 + h * 16 + e;
        #pragma unroll
        for (int r = 0; r < 8; ++r) dst[r * 128] = acc[r] * rs;
    } else {
        #pragma unroll
        for (int r = 0; r < 8; ++r) {
            const int row = row0 + r;
            const int j = row >> 2, b = row & 3;
            ksT[((e >> 2) * LK + j) * 128 + (b * 8 + h) * 4 + (e & 3)] = acc[r] * rs;
        }
    }
}

// ---------------------------------------------------------------------------
// Score (R12 shell), polynomial sinc with packed-f32 math. Per pair
// p=(d,d+8): u=q-k (pk), u2=max(|u|,EPS) (2 scalar), n=rndne(u2) (2 scalar),
// f=u2-n (pk), Horner deg-13 in f2 (7 pk), pn*=f*P (pk), pd*=u2 (pk).
// Zero transcendentals; no extra memory streams vs R12.
// ---------------------------------------------------------------------------
__global__ __launch_bounds__(256, 4) void score_kernel(
    const float* __restrict__ qs, const float* __restrict__ ksT,
    float* __restrict__ out)
{
    __shared__ float qt[IT * 32 * QSTRIDE];       // 20480 B
    const int t = threadIdx.x;
    const int bh = t & 31;
    const int js = t >> 5;                        // 0..7
    const int key = bh >> 3;                      // 0..3 plane-permutation key
    const int i0 = blockIdx.x * IT;               // 32 i-tiles
    const int j = blockIdx.y * 8 + js;            // 64 j-tiles of 8

    constexpr float i2c = INV2PI * INV2PI;
    constexpr float i4c = i2c * i2c;
    constexpr float i8c = i4c * i4c;
    constexpr float C16 = i8c * i8c;              // (2pi)^-16
    constexpr float EPS = 2.0e-4f * INV2PI;       // 3.18e-5 rev; EPS^8 > FLT_MIN

    // stage q-tile (identical to R12; row element order is pre-permuted)
    {
        const float* src = qs + i0 * 32 * 16;
        #pragma unroll
        for (int rep = 0; rep < 4; ++rep) {
            const int c4 = rep * 256 + t;         // float4 chunk id, 0..1023
            const int row = c4 >> 2, cc = (c4 & 3) * 4;
            const float4 v = *(const float4*)(src + c4 * 4);
            *(float4*)(&qt[row * QSTRIDE + cc]) = v;
        }
    }

    // k resident as 8 v2f pairs (plane-permuted to match swizzled q reads)
    v2f kp[8];
    #pragma unroll
    for (int s = 0; s < 4; ++s) {
        const int plane = s ^ key;
        const float4 v = *(const float4*)(ksT + (plane * LK + j) * 128 + bh * 4);
        kp[s * 2 + 0] = v2f{v.x, v.y};
        kp[s * 2 + 1] = v2f{v.z, v.w};
    }
    __syncthreads();

    #pragma unroll 2
    for (int ii = 0; ii < IT; ++ii) {
        const float* qrow = &qt[(ii * 32 + bh) * QSTRIDE];
        v2f qp[8];
        #pragma unroll
        for (int s = 0; s < 4; ++s) {
            const float4 v = *(const float4*)(qrow + ((s ^ key) << 2));
            qp[s * 2 + 0] = v2f{v.x, v.y};
            qp[s * 2 + 1] = v2f{v.z, v.w};
        }
        v2f pnA = v2f{1.f, 1.f}, pdA = v2f{1.f, 1.f};
        v2f pnB = v2f{1.f, 1.f}, pdB = v2f{1.f, 1.f};
        #pragma unroll
        for (int p = 0; p < 8; ++p) {
            const v2f u = qp[p] - kp[p];                       // pk_add(neg)
            v2f a;
            a.x = fmaxf(__builtin_fabsf(u.x), EPS);            // scalar x2
            a.y = fmaxf(__builtin_fabsf(u.y), EPS);
            v2f n;
            n.x = __builtin_rintf(a.x);                        // v_rndne x2
            n.y = __builtin_rintf(a.y);
            const v2f f  = a - n;                              // pk
            const v2f f2 = f * f;                              // pk
            v2f pl = v2f{SC13, SC13};
            pl = pl * f2 + v2f{SC11, SC11};                    // pk_fma x6
            pl = pl * f2 + v2f{SC9,  SC9};
            pl = pl * f2 + v2f{SC7,  SC7};
            pl = pl * f2 + v2f{SC5,  SC5};
            pl = pl * f2 + v2f{SC3,  SC3};
            pl = pl * f2 + v2f{SC1,  SC1};
            const v2f s = f * pl;                              // sin(2pi*u2)
            if (p < 4) { pnA *= s; pdA *= a; }
            else       { pnB *= s; pdB *= a; }
        }
        const float n0 = pnA.x * pnB.x, d0 = pdA.x * pdB.x;    // d-half 0
        const float n1 = pnA.y * pnB.y, d1 = pdA.y * pdB.y;    // d-half 1
        const float r0 = n0 * __builtin_amdgcn_rcpf(d0);
        const float r1 = n1 * __builtin_amdgcn_rcpf(d1);
        out[((i0 + ii) * LK + j) * 32 + bh] = __builtin_fabsf(r0 * r1) * C16;
    }
}

extern "C" void kernel_launch(void* const* d_in, const int* in_sizes, int n_in,
                              void* d_out, int out_size, void* d_ws, size_t ws_size,
                              hipStream_t stream) {
    const float* hh     = (const float*)d_in[0];
    const float* mems   = (const float*)d_in[1];
    const float* Wq     = (const float*)d_in[2];
    const float* Wk     = (const float*)d_in[3];
    const float* paramR = (const float*)d_in[4];
    float* out = (float*)d_out;

    float* qs  = (float*)d_ws;                // 131072 floats
    float* ksT = qs + LQ * BB * DM;           // 262144 floats

    proj_kernel<<<384, 128, 0, stream>>>(hh, mems, Wq, Wk, paramR, qs, ksT);
    score_kernel<<<dim3(LQ / IT, LK / 8), 256, 0, stream>>>(qs, ksT, out);
}

// Round 20
// 30.709 us; speedup vs baseline: 1.5495x; 1.2094x over previous
//
#include <hip/hip_runtime.h>
#include <math.h>

#define LQ 256
#define MEML 256
#define LK 512
#define BB 4
#define NH 8
#define DM 128

#define IT 8                  // i-tile per score block (20 KB LDS)
#define QSTRIDE 20            // LDS q row stride (floats)

constexpr float INV2PI = 0.15915494309189535f;

// ---------------------------------------------------------------------------
// Projection (identical to R12), pre-scaled by paramR[h]/(2*pi):
//   qs[(i*4+b)*128 + h*16+d]
//   ksT[((d>>2)*512 + j)*128 + (b*8+h)*4 + (d&3)]
// ---------------------------------------------------------------------------
__global__ __launch_bounds__(128) void proj_kernel(
    const float* __restrict__ hh, const float* __restrict__ mems,
    const float* __restrict__ Wq, const float* __restrict__ Wk,
    const float* __restrict__ paramR,
    float* __restrict__ qs, float* __restrict__ ksT)
{
    __shared__ float x[8 * 128];
    const int blk = blockIdx.x;
    const int t = threadIdx.x;
    const bool isQ = (blk < 128);                 // 128 q-blocks, 256 k-blocks
    const int row0 = isQ ? blk * 8 : (blk - 128) * 8;
    const float* __restrict__ W = isQ ? Wq : Wk;

    for (int r = 0; r < 8; ++r) {
        const int row = row0 + r;
        const float* src = isQ ? (hh + row * DM)
                               : ((row < MEML * BB) ? (mems + row * DM)
                                                    : (hh + (row - MEML * BB) * DM));
        x[r * 128 + t] = src[t];
    }
    __syncthreads();

    float acc[8] = {0, 0, 0, 0, 0, 0, 0, 0};
    const float* wrow = W + t * DM;
    for (int k = 0; k < DM; k += 4) {
        const float4 w = *(const float4*)(wrow + k);
        #pragma unroll
        for (int r = 0; r < 8; ++r) {
            acc[r] += x[r * 128 + k + 0] * w.x + x[r * 128 + k + 1] * w.y
                    + x[r * 128 + k + 2] * w.z + x[r * 128 + k + 3] * w.w;
        }
    }
    const int h = t >> 4, d = t & 15;
    const float rs = paramR[h] * INV2PI;
    if (isQ) {
        float* dst = qs + row0 * 128 + t;
        #pragma unroll
        for (int r = 0; r < 8; ++r) dst[r * 128] = acc[r] * rs;
    } else {
        #pragma unroll
        for (int r = 0; r < 8; ++r) {
            const int row = row0 + r;
            const int j = row >> 2, b = row & 3;
            ksT[((d >> 2) * LK + j) * 128 + (b * 8 + h) * 4 + (d & 3)] = acc[r] * rs;
        }
    }
}

// ---------------------------------------------------------------------------
// Score, d-SPLIT across half-waves: thread (bh=t&31, dh=(t>>5)&1, js=t>>6)
// owns 8 d's -> k[8]+q[8]+acc ~= 40 VGPR, fits the 64-cap WITH headroom so
// the compiler cannot be pressured into per-ii k reloads (R14 showed
// VGPR_Count=32 => rematerialized k = vmcnt stalls every ii — the suspected
// invariant ~10us stall). Halves combine via ONE __shfl_xor(r_half, 32) per
// output (each half does its own 8-factor ratio incl. rcp; same math).
// IT=8 q-tile in LDS (20 KB, 2-chunk swizzle -> free 2-way); grid (32,128) =
// 4096 blocks = 2 generations at 8 blocks/CU for ramp/tail overlap.
// ---------------------------------------------------------------------------
__global__ __launch_bounds__(256, 8) void score_kernel(
    const float* __restrict__ qs, const float* __restrict__ ksT,
    float* __restrict__ out)
{
    __shared__ float qt[IT * 32 * QSTRIDE];       // 20480 B
    const int t = threadIdx.x;
    const int bh = t & 31;
    const int dh = (t >> 5) & 1;                  // d-half owner (0: d0-7, 1: d8-15)
    const int js = t >> 6;                        // 0..3
    const int key1 = (bh >> 3) & 1;               // 2-chunk swizzle key
    const int i0 = blockIdx.x * IT;               // 32 i-tiles
    const int j = blockIdx.y * 4 + js;            // 128 j-tiles of 4

    constexpr float i2 = INV2PI * INV2PI;
    constexpr float i4 = i2 * i2;
    constexpr float i8 = i4 * i4;
    constexpr float C16 = i8 * i8;                // (2pi)^-16
    constexpr float EPS = 2.0e-4f * INV2PI;       // 3.18e-5 rev; EPS^8 > FLT_MIN

    // stage q-tile (identical to R12)
    {
        const float* src = qs + i0 * 32 * 16;
        #pragma unroll
        for (int rep = 0; rep < 4; ++rep) {
            const int c4 = rep * 256 + t;         // float4 chunk id, 0..1023
            const int row = c4 >> 2, cc = (c4 & 3) * 4;
            const float4 v = *(const float4*)(src + c4 * 4);
            *(float4*)(&qt[row * QSTRIDE + cc]) = v;
        }
    }

    // k: only THIS half's 8 floats, chunk-permuted to match swizzled q reads
    float k[8];
    #pragma unroll
    for (int s = 0; s < 2; ++s) {
        const int plane = dh * 2 + (s ^ key1);
        const float4 v = *(const float4*)(ksT + (plane * LK + j) * 128 + bh * 4);
        k[s * 4 + 0] = v.x; k[s * 4 + 1] = v.y;
        k[s * 4 + 2] = v.z; k[s * 4 + 3] = v.w;
    }
    __syncthreads();

    #pragma unroll 2
    for (int ii = 0; ii < IT; ++ii) {
        const float* qrow = &qt[(ii * 32 + bh) * QSTRIDE + dh * 8];
        float q[8];
        #pragma unroll
        for (int s = 0; s < 2; ++s) {
            const float4 v = *(const float4*)(qrow + ((s ^ key1) << 2));
            q[s * 4 + 0] = v.x; q[s * 4 + 1] = v.y;
            q[s * 4 + 2] = v.z; q[s * 4 + 3] = v.w;
        }
        float pn = 1.f, pd = 1.f;
        #pragma unroll
        for (int d = 0; d < 8; ++d) {
            const float u2 = fmaxf(__builtin_fabsf(q[d] - k[d]), EPS);
            const float s = __builtin_amdgcn_sinf(u2);   // sin(2pi*u2)
            pn *= s; pd *= u2;
        }
        const float rh = pn * __builtin_amdgcn_rcpf(pd); // |.| <= (2pi)^8
        const float ro = __shfl_xor(rh, 32, 64);         // partner half's ratio
        if (dh == 0)
            out[((i0 + ii) * LK + j) * 32 + bh] = __builtin_fabsf(rh * ro) * C16;
    }
}

extern "C" void kernel_launch(void* const* d_in, const int* in_sizes, int n_in,
                              void* d_out, int out_size, void* d_ws, size_t ws_size,
                              hipStream_t stream) {
    const float* hh     = (const float*)d_in[0];
    const float* mems   = (const float*)d_in[1];
    const float* Wq     = (const float*)d_in[2];
    const float* Wk     = (const float*)d_in[3];
    const float* paramR = (const float*)d_in[4];
    float* out = (float*)d_out;

    float* qs  = (float*)d_ws;                // 131072 floats
    float* ksT = qs + LQ * BB * DM;           // 262144 floats

    proj_kernel<<<384, 128, 0, stream>>>(hh, mems, Wq, Wk, paramR, qs, ksT);
    score_kernel<<<dim3(LQ / IT, LK / 4), 256, 0, stream>>>(qs, ksT, out);
}